// Round 6
// baseline (168.223 us; speedup 1.0000x reference)
//
#include <hip/hip_runtime.h>
#include <cmath>

#define A_CNT 196416
#define C_CNT 90
#define TOPK 100u
#define CAPB 2048
#define TB 64                          // anchors per reduce tile/block
#define NTILE (A_CNT / TB)             // 3069 (exact: 196416 = 64*3069)

// ws layout (bytes):
//   [0, 785664)          keys[A]   (uint32 monotonic score keys; 0 = below threshold)
//   [785664, 789760)     hist1[1024] (coarse: idx 0 = zero-key, 1..565 = top16-0x3D4B)
//   [789760, 789824)     ctrl[16]: 0=binB(top16) 1=G 5=candA_cnt 6=candB_cnt
//   [789824, 790336)     candA[128]  (keys strictly above binB; count = G < 100)
//   [790336, 798528)     candB[2048] (keys with top16 == binB; expected ~55)
#define OFF_HIST1 785664u
#define OFF_CTRL  789760u
#define OFF_CANDA 789824u
#define OFF_CANDB 790336u

// Kernel 1: staged-transpose max-reduce. 64 anchors/block = 5760 floats =
// 23 KB LDS (6 blocks/CU resident). Phase 1: 1440 float4 staged by 256 threads
// (6 fully-coalesced 1 KB wave-loads each). Phase 2: 4 threads/anchor scan
// 12/12/12/9 float2 from LDS (<=4-way bank aliasing ~1.58x), 2 shfl_xor merge.
// One barrier between phases; intrinsic model ~13-16 us device-wide.
__global__ __launch_bounds__(256) void k_reduce(const float* __restrict__ cls,
                                                unsigned* __restrict__ keys,
                                                unsigned* __restrict__ hist1) {
    __shared__ alignas(16) float smem[TB * C_CNT];   // 23040 B
    __shared__ unsigned lhist[576];
    const int t = threadIdx.x;
    for (int j = t; j < 576; j += 256) lhist[j] = 0u;

    const float4* __restrict__ g4 = (const float4*)cls + (size_t)blockIdx.x * 1440;
    float4* __restrict__ s4 = (float4*)smem;
#pragma unroll
    for (int i = 0; i < 6; ++i) {
        int c = t + 256 * i;                         // 1440 chunks < 1536
        if (c < 1440) s4[c] = g4[c];
    }
    __syncthreads();                                 // orders lhist init too

    const int r = t >> 2, h = t & 3;                 // anchor-in-tile, quarter
    const float2* row = (const float2*)(smem + r * C_CNT) + h * 12;
    const int n2 = (h < 3) ? 12 : 9;                 // 12+12+12+9 = 45 float2 = 90
    float m = -INFINITY;
#pragma unroll 3
    for (int i = 0; i < n2; ++i) {
        float2 v = row[i];
        m = fmaxf(m, fmaxf(v.x, v.y));
    }
    m = fmaxf(m, __shfl_xor(m, 1));
    m = fmaxf(m, __shfl_xor(m, 2));
    if (h == 0) {
        float pr = 1.0f / (1.0f + expf(-m));         // sigmoid(max) == max(sigmoid)
        unsigned k = (pr > 0.05f) ? __float_as_uint(pr) : 0u;
        keys[blockIdx.x * TB + r] = k;               // 16 consecutive dwords per wave
        unsigned hi = k ? (min(k >> 16, 0x3F80u) - 0x3D4Bu) : 0u;  // 0=zeros, 1..565
        atomicAdd(&lhist[hi], 1u);
    }
    __syncthreads();
    for (int j = t; j < 576; j += 256) {
        unsigned c = lhist[j];
        if (c) atomicAdd(&hist1[j], c);
    }
}

// Suffix-scan select over the 1024-bin coarse histogram (single block).
// ctrl[0] = binB (true top16 bits, or 0 for the zero-key bin)
// ctrl[1] = G = # keys strictly above binB (< 100 by construction)
__global__ __launch_bounds__(256) void k_scan(const unsigned* __restrict__ hist,
                                              unsigned* __restrict__ ctrl) {
    __shared__ unsigned sdata[256];
    __shared__ unsigned sbin[2];
    const int t = threadIdx.x;
    const unsigned target = TOPK;

    uint4 u = ((const uint4*)hist)[t];               // 4 bins per thread
    unsigned s = u.x + u.y + u.z + u.w;
    sdata[t] = s;
    for (int d = 1; d < 256; d <<= 1) {              // Hillis-Steele inclusive suffix scan
        __syncthreads();
        unsigned add = (t + d < 256) ? sdata[t + d] : 0u;
        __syncthreads();
        sdata[t] += add;
    }
    __syncthreads();
    {
        unsigned mysuf  = sdata[t];
        unsigned nxtsuf = (t < 255) ? sdata[t + 1] : 0u;
        if (nxtsuf < target && mysuf >= target) { sbin[0] = (unsigned)t; sbin[1] = nxtsuf; }
    }
    __syncthreads();
    const unsigned chunkB = sbin[0];
    const unsigned gAbove = sbin[1];

    unsigned v = (t < 4) ? hist[chunkB * 4 + t] : 0u;
    sdata[t] = v;
    for (int d = 1; d < 256; d <<= 1) {
        __syncthreads();
        unsigned add = (t + d < 256) ? sdata[t + d] : 0u;
        __syncthreads();
        sdata[t] += add;
    }
    __syncthreads();
    {
        unsigned mysuf  = sdata[t] + gAbove;
        unsigned nxtsuf = ((t < 255) ? sdata[t + 1] : 0u) + gAbove;
        if (nxtsuf < target && mysuf >= target) {
            unsigned bin = chunkB * 4 + (unsigned)t;  // hist index: 0=zeros, 1..565
            ctrl[0] = bin ? (bin + 0x3D4Bu) : 0u;     // back to true top-16 bits
            ctrl[1] = nxtsuf;
        }
    }
}

// One pass over keys: collect strictly-above (candA, exact G<100 entries) and
// in-bin (candB, expected ~55, cap 2048) candidate anchor indices.
__global__ __launch_bounds__(256) void k_gather(const unsigned* __restrict__ keys,
                                                unsigned* __restrict__ ctrl,
                                                unsigned* __restrict__ candA,
                                                unsigned* __restrict__ candB) {
    const unsigned binB = ctrl[0];
    const int i4 = blockIdx.x * 256 + threadIdx.x;
    if (i4 >= A_CNT / 4) return;
    uint4 k = ((const uint4*)keys)[i4];
    const unsigned base = (unsigned)(4 * i4);
#pragma unroll
    for (int j = 0; j < 4; ++j) {
        unsigned kk = (j == 0) ? k.x : (j == 1) ? k.y : (j == 2) ? k.z : k.w;
        unsigned t16 = kk >> 16;
        if (t16 > binB) {
            unsigned q = atomicAdd(&ctrl[5], 1u);
            if (q < 128u) candA[q] = base + j;
        } else if (t16 == binB) {
            unsigned q = atomicAdd(&ctrl[6], 1u);
            if (q < (unsigned)CAPB) candB[q] = base + j;
        }
    }
}

// Final: exact rank of candidates by (key desc, idx asc) — lax.top_k stable
// order — from LDS; take all of candA then top-(100-G) of candB. Then argmax
// over RAW logits (sigmoid monotonic; strict > = first-index tie), decode+clip,
// write [boxes(400) | scores(100) | classes(100)] as f32.
__global__ __launch_bounds__(256) void k_final(const float* __restrict__ cls,
                                               const float* __restrict__ reg,
                                               const float* __restrict__ anc,
                                               const unsigned* __restrict__ ctrl,
                                               const unsigned* __restrict__ candA,
                                               const unsigned* __restrict__ candB,
                                               const unsigned* __restrict__ keys,
                                               float* __restrict__ out) {
    __shared__ unsigned sAi[128], sAk[128];
    __shared__ unsigned sBi[CAPB], sBk[CAPB];
    __shared__ unsigned sel[TOPK];
    const int t = threadIdx.x;
    const unsigned nA = min(ctrl[5], 128u);          // exact G < 100
    const unsigned nB = min(ctrl[6], (unsigned)CAPB);
    const unsigned need = TOPK - nA;                 // >= 1; count-in-bin >= need

    if (t < (int)nA) { unsigned i = candA[t]; sAi[t] = i; sAk[t] = keys[i]; }
    for (unsigned e = (unsigned)t; e < nB; e += 256u) {
        unsigned i = candB[e]; sBi[e] = i; sBk[e] = keys[i];
    }
    __syncthreads();

    if (t < (int)nA) {
        unsigned mi = sAi[t], mk = sAk[t], r = 0;
        for (unsigned j = 0; j < nA; ++j) {
            unsigned ok = sAk[j];
            if (ok > mk || (ok == mk && sAi[j] < mi)) r++;
        }
        sel[r] = mi;
    }
    for (unsigned e = (unsigned)t; e < nB; e += 256u) {
        unsigned mi = sBi[e], mk = sBk[e], r = 0;
        for (unsigned j = 0; j < nB; ++j) {
            unsigned ok = sBk[j];
            if (ok > mk || (ok == mk && sBi[j] < mi)) r++;
        }
        if (r < need) sel[nA + r] = mi;
    }
    __syncthreads();

    if (t < (int)TOPK) {
        const unsigned a = sel[t];
        const float2* row = (const float2*)(cls + (size_t)a * C_CNT);
        float bv = -INFINITY; int bi = 0;
#pragma unroll 5
        for (int c = 0; c < 45; ++c) {
            float2 v = row[c];
            if (v.x > bv) { bv = v.x; bi = 2 * c; }
            if (v.y > bv) { bv = v.y; bi = 2 * c + 1; }
        }
        float score = __uint_as_float(keys[a]);      // prob bits, or 0.0 if thresholded
        float x1a = anc[a * 4 + 0], y1a = anc[a * 4 + 1];
        float x2a = anc[a * 4 + 2], y2a = anc[a * 4 + 3];
        float wa = x2a - x1a, ha = y2a - y1a;
        float cxa = x1a + 0.5f * wa, cya = y1a + 0.5f * ha;
        float dx = reg[a * 4 + 0] * 0.1f, dy = reg[a * 4 + 1] * 0.1f;
        float dw = reg[a * 4 + 2] * 0.2f, dh = reg[a * 4 + 3] * 0.2f;
        float cx = cxa + dx * wa, cy = cya + dy * ha;
        float w = expf(dw) * wa, h = expf(dh) * ha;
        out[t * 4 + 0] = fmaxf(cx - 0.5f * w, 0.0f);
        out[t * 4 + 1] = fmaxf(cy - 0.5f * h, 0.0f);
        out[t * 4 + 2] = fminf(cx + 0.5f * w, 1024.0f);
        out[t * 4 + 3] = fminf(cy + 0.5f * h, 1024.0f);
        out[400 + t] = score;
        out[500 + t] = (float)bi;
    }
}

extern "C" void kernel_launch(void* const* d_in, const int* in_sizes, int n_in,
                              void* d_out, int out_size, void* d_ws, size_t ws_size,
                              hipStream_t stream) {
    const float* reg = (const float*)d_in[1];
    const float* cls = (const float*)d_in[2];
    const float* anc = (const float*)d_in[3];
    float* out = (float*)d_out;
    char* ws = (char*)d_ws;
    unsigned* keys  = (unsigned*)ws;
    unsigned* hist1 = (unsigned*)(ws + OFF_HIST1);
    unsigned* ctrl  = (unsigned*)(ws + OFF_CTRL);
    unsigned* candA = (unsigned*)(ws + OFF_CANDA);
    unsigned* candB = (unsigned*)(ws + OFF_CANDB);

    // hist1 (4 KB) + ctrl (64 B) are contiguous -> one memset covers both.
    hipMemsetAsync(hist1, 0, 4096 + 64, stream);
    k_reduce<<<NTILE, 256, 0, stream>>>(cls, keys, hist1);
    k_scan<<<1, 256, 0, stream>>>(hist1, ctrl);
    k_gather<<<192, 256, 0, stream>>>(keys, ctrl, candA, candB);
    k_final<<<1, 256, 0, stream>>>(cls, reg, anc, ctrl, candA, candB, keys, out);
}

// Round 7
// 151.817 us; speedup vs baseline: 1.1081x; 1.1081x over previous
//
#include <hip/hip_runtime.h>
#include <cmath>

#define A_CNT 196416
#define C_CNT 90
#define PAIRS (A_CNT / 2)            // 98208 = 12276 * 8 pairs
#define WITERS 12276                 // wave-iterations (8 pairs per wave-iter)
#define TOPK 100u
#define CAPB 2048
#define NB_RED 1536                  // 6144 waves -> exactly ~2 iters/wave
#define NB_GAT 192

// ws layout (bytes):
//   [0, 785664)          keys[A]   (uint32 monotonic score keys; 0 = below threshold)
//   [785664, 789760)     hist1[1024] (coarse: idx 0 = zero-key, 1..565 = top16-0x3D4B)
//   [789760, 789824)     ctrl[16]: 0=binB(top16) 1=G 5=candA_cnt 6=candB_cnt 8=doneR 9=doneG
//   [789824, 790336)     candA[128]  (keys strictly above binB; count = G < 100)
//   [790336, 798528)     candB[2048] (keys with top16 == binB)
#define OFF_HIST1 785664u
#define OFF_CTRL  789760u
#define OFF_CANDA 789824u
#define OFF_CANDB 790336u

#define AGENT_LD(p)    __hip_atomic_load((p), __ATOMIC_RELAXED, __HIP_MEMORY_SCOPE_AGENT)
#define AGENT_ST(p, v) __hip_atomic_store((p), (v), __ATOMIC_RELAXED, __HIP_MEMORY_SCOPE_AGENT)

// Kernel 1: 8 lanes cooperate on one anchor-pair (720 B = 45 float4) — best
// observed structure (R5). Fused tail: the LAST block (done-counter) runs the
// 1024-bin suffix-scan select and publishes binB/G in ctrl.
// Visibility argument: every thread's hist1 atomics complete (vmcnt) at the
// __syncthreads before t0's done-increment, so a block observing done==NB-1
// observes all histogram contributions; it reads hist1 with agent-scope loads
// to bypass any stale local cache (G16).
__global__ __launch_bounds__(256, 4) void k_reduce(const float* __restrict__ cls,
                                                   unsigned* __restrict__ keys,
                                                   unsigned* __restrict__ hist1,
                                                   unsigned* __restrict__ ctrl) {
    __shared__ unsigned lhist[576];
    __shared__ unsigned sdata[256];
    __shared__ unsigned sbin[2];
    __shared__ int sflag;
    const int t = threadIdx.x;
    for (int j = t; j < 576; j += 256) lhist[j] = 0u;
    __syncthreads();

    const int lane = t & 63;
    const int g = lane >> 3, s = lane & 7;
    const int wid = blockIdx.x * 4 + (t >> 6);
    const int nw = NB_RED * 4;
    const float4* __restrict__ cls4 = (const float4*)cls;

    for (int w = wid; w < WITERS; w += nw) {
        const int p = w * 8 + g;                     // pair index (always < PAIRS)
        const float4* __restrict__ r4 = cls4 + (size_t)p * 45;
        float m0 = -INFINITY, m1 = -INFINITY;
#pragma unroll
        for (int i = 0; i < 6; ++i) {
            const int j = s + 8 * i;                 // 45 chunks: s<5 -> 6, s>=5 -> 5
            if (j < 45) {
                float4 v = r4[j];
                float a01 = fmaxf(v.x, v.y), a23 = fmaxf(v.z, v.w);
                float all = fmaxf(a01, a23);
                if (j < 22)      m0 = fmaxf(m0, all);
                else if (j > 22) m1 = fmaxf(m1, all);
                else { m0 = fmaxf(m0, a01); m1 = fmaxf(m1, a23); }  // 88,89|90,91 split
            }
        }
#pragma unroll
        for (int d = 1; d < 8; d <<= 1) {            // reduce across the 8-lane group
            m0 = fmaxf(m0, __shfl_xor(m0, d));
            m1 = fmaxf(m1, __shfl_xor(m1, d));
        }
        if (s == 0) {
            float p0 = 1.0f / (1.0f + expf(-m0));    // sigmoid(max) == max(sigmoid)
            float p1 = 1.0f / (1.0f + expf(-m1));
            unsigned k0 = (p0 > 0.05f) ? __float_as_uint(p0) : 0u;
            unsigned k1 = (p1 > 0.05f) ? __float_as_uint(p1) : 0u;
            *(uint2*)(keys + 2 * p) = make_uint2(k0, k1);
            unsigned h0 = k0 ? (min(k0 >> 16, 0x3F80u) - 0x3D4Bu) : 0u;  // 0=zeros, 1..565
            unsigned h1 = k1 ? (min(k1 >> 16, 0x3F80u) - 0x3D4Bu) : 0u;
            atomicAdd(&lhist[h0], 1u);
            atomicAdd(&lhist[h1], 1u);
        }
    }
    __syncthreads();
    for (int j = t; j < 576; j += 256) {
        unsigned c = lhist[j];
        if (c) atomicAdd(&hist1[j], c);
    }
    __syncthreads();                                 // drains each thread's atomics (vmcnt)
    if (t == 0) sflag = (atomicAdd(&ctrl[8], 1u) == NB_RED - 1u) ? 1 : 0;
    __syncthreads();
    if (!sflag) return;

    // ---- fused k_scan (last block only; uniform branch, barriers legal) ----
    const unsigned target = TOPK;
    unsigned ssum = 0;
#pragma unroll
    for (int j = 0; j < 4; ++j) ssum += AGENT_LD(&hist1[t * 4 + j]);
    sdata[t] = ssum;
    for (int d = 1; d < 256; d <<= 1) {              // Hillis-Steele inclusive suffix scan
        __syncthreads();
        unsigned add = (t + d < 256) ? sdata[t + d] : 0u;
        __syncthreads();
        sdata[t] += add;
    }
    __syncthreads();
    {
        unsigned mysuf  = sdata[t];
        unsigned nxtsuf = (t < 255) ? sdata[t + 1] : 0u;
        if (nxtsuf < target && mysuf >= target) { sbin[0] = (unsigned)t; sbin[1] = nxtsuf; }
    }
    __syncthreads();
    const unsigned chunkB = sbin[0];
    const unsigned gAbove = sbin[1];
    unsigned v = (t < 4) ? AGENT_LD(&hist1[chunkB * 4 + t]) : 0u;
    sdata[t] = v;
    for (int d = 1; d < 256; d <<= 1) {
        __syncthreads();
        unsigned add = (t + d < 256) ? sdata[t + d] : 0u;
        __syncthreads();
        sdata[t] += add;
    }
    __syncthreads();
    {
        unsigned mysuf  = sdata[t] + gAbove;
        unsigned nxtsuf = ((t < 255) ? sdata[t + 1] : 0u) + gAbove;
        if (nxtsuf < target && mysuf >= target) {
            unsigned bin = chunkB * 4 + (unsigned)t;  // hist index: 0=zeros, 1..565
            ctrl[0] = bin ? (bin + 0x3D4Bu) : 0u;     // true top-16 bits
            ctrl[1] = nxtsuf;                         // G < 100
        }
    }
}

// Kernel 2: gather candidates (one uint4 pass over keys), then the LAST block
// runs the full ranking + argmax + box decode (fused k_final).
// candA/candB payloads use agent-scope stores; reader uses agent-scope loads.
__global__ __launch_bounds__(256) void k_gather(const float* __restrict__ cls,
                                                const float* __restrict__ reg,
                                                const float* __restrict__ anc,
                                                const unsigned* __restrict__ keys,
                                                unsigned* __restrict__ ctrl,
                                                unsigned* __restrict__ candA,
                                                unsigned* __restrict__ candB,
                                                float* __restrict__ out) {
    __shared__ unsigned sAi[128], sAk[128];
    __shared__ unsigned sBi[CAPB], sBk[CAPB];
    __shared__ unsigned sel[TOPK];
    __shared__ int sflag;
    const int t = threadIdx.x;

    const unsigned binB = ctrl[0];                   // prev kernel -> plain load ok
    const int i4 = blockIdx.x * 256 + t;
    if (i4 < A_CNT / 4) {
        uint4 k = ((const uint4*)keys)[i4];
        const unsigned base = (unsigned)(4 * i4);
#pragma unroll
        for (int j = 0; j < 4; ++j) {
            unsigned kk = (j == 0) ? k.x : (j == 1) ? k.y : (j == 2) ? k.z : k.w;
            unsigned t16 = kk >> 16;
            if (t16 > binB) {
                unsigned q = atomicAdd(&ctrl[5], 1u);
                if (q < 128u) AGENT_ST(&candA[q], base + j);
            } else if (t16 == binB) {
                unsigned q = atomicAdd(&ctrl[6], 1u);
                if (q < (unsigned)CAPB) AGENT_ST(&candB[q], base + j);
            }
        }
    }
    __syncthreads();                                 // drains this thread's stores/atomics
    if (t == 0) sflag = (atomicAdd(&ctrl[9], 1u) == (unsigned)NB_GAT - 1u) ? 1 : 0;
    __syncthreads();
    if (!sflag) return;

    // ---- fused k_final (last block only) ----
    const unsigned nA = min(AGENT_LD(&ctrl[5]), 128u);   // exact G < 100
    const unsigned nB = min(AGENT_LD(&ctrl[6]), (unsigned)CAPB);
    const unsigned need = TOPK - nA;                     // >= 1; in-bin count >= need

    if (t < (int)nA) { unsigned i = AGENT_LD(&candA[t]); sAi[t] = i; sAk[t] = keys[i]; }
    for (unsigned e = (unsigned)t; e < nB; e += 256u) {
        unsigned i = AGENT_LD(&candB[e]); sBi[e] = i; sBk[e] = keys[i];
    }
    __syncthreads();

    if (t < (int)nA) {                               // rank strictly-above candidates
        unsigned mi = sAi[t], mk = sAk[t], r = 0;
        for (unsigned j = 0; j < nA; ++j) {
            unsigned ok = sAk[j];
            if (ok > mk || (ok == mk && sAi[j] < mi)) r++;
        }
        sel[r] = mi;
    }
    for (unsigned e = (unsigned)t; e < nB; e += 256u) {  // in-bin: (key desc, idx asc)
        unsigned mi = sBi[e], mk = sBk[e], r = 0;
        for (unsigned j = 0; j < nB; ++j) {
            unsigned ok = sBk[j];
            if (ok > mk || (ok == mk && sBi[j] < mi)) r++;
        }
        if (r < need) sel[nA + r] = mi;
    }
    __syncthreads();

    if (t < (int)TOPK) {
        const unsigned a = sel[t];
        const float2* row = (const float2*)(cls + (size_t)a * C_CNT);
        float bv = -INFINITY; int bi = 0;
#pragma unroll 5
        for (int c = 0; c < 45; ++c) {               // argmax over RAW logits (sigmoid
            float2 v = row[c];                       // monotonic; strict > = first-index)
            if (v.x > bv) { bv = v.x; bi = 2 * c; }
            if (v.y > bv) { bv = v.y; bi = 2 * c + 1; }
        }
        float score = __uint_as_float(keys[a]);      // prob bits, or 0.0 if thresholded
        float x1a = anc[a * 4 + 0], y1a = anc[a * 4 + 1];
        float x2a = anc[a * 4 + 2], y2a = anc[a * 4 + 3];
        float wa = x2a - x1a, ha = y2a - y1a;
        float cxa = x1a + 0.5f * wa, cya = y1a + 0.5f * ha;
        float dx = reg[a * 4 + 0] * 0.1f, dy = reg[a * 4 + 1] * 0.1f;
        float dw = reg[a * 4 + 2] * 0.2f, dh = reg[a * 4 + 3] * 0.2f;
        float cx = cxa + dx * wa, cy = cya + dy * ha;
        float w = expf(dw) * wa, h = expf(dh) * ha;
        out[t * 4 + 0] = fmaxf(cx - 0.5f * w, 0.0f);
        out[t * 4 + 1] = fmaxf(cy - 0.5f * h, 0.0f);
        out[t * 4 + 2] = fminf(cx + 0.5f * w, 1024.0f);
        out[t * 4 + 3] = fminf(cy + 0.5f * h, 1024.0f);
        out[400 + t] = score;
        out[500 + t] = (float)bi;
    }
}

extern "C" void kernel_launch(void* const* d_in, const int* in_sizes, int n_in,
                              void* d_out, int out_size, void* d_ws, size_t ws_size,
                              hipStream_t stream) {
    const float* reg = (const float*)d_in[1];
    const float* cls = (const float*)d_in[2];
    const float* anc = (const float*)d_in[3];
    float* out = (float*)d_out;
    char* ws = (char*)d_ws;
    unsigned* keys  = (unsigned*)ws;
    unsigned* hist1 = (unsigned*)(ws + OFF_HIST1);
    unsigned* ctrl  = (unsigned*)(ws + OFF_CTRL);
    unsigned* candA = (unsigned*)(ws + OFF_CANDA);
    unsigned* candB = (unsigned*)(ws + OFF_CANDB);

    // hist1 (4 KB) + ctrl (64 B, incl. done counters) are contiguous.
    hipMemsetAsync(hist1, 0, 4096 + 64, stream);
    k_reduce<<<NB_RED, 256, 0, stream>>>(cls, keys, hist1, ctrl);
    k_gather<<<NB_GAT, 256, 0, stream>>>(cls, reg, anc, keys, ctrl, candA, candB, out);
}